// Round 1
// 142.170 us; speedup vs baseline: 1.0423x; 1.0423x over previous
//
#include <hip/hip_runtime.h>
#include <hip/hip_bf16.h>

#define MPTS 50000
#define NPTS 100000
#define KK 15
#define TM 16      // queries per block; 8 waves, wave owns 2 -> barrier-free A/B phases
#define WTP 1036   // wtw row stride (shorts): 518 b32 = 6 mod 32 -> phase-C A reads uniform banks
#define STP 36     // stage row stride (shorts): 18 b32 -> all stage ops <=2-way

typedef __attribute__((ext_vector_type(8))) short short8;
typedef __attribute__((ext_vector_type(4))) short short4v;
typedef __attribute__((ext_vector_type(4))) float floatx4;

static __device__ __forceinline__ unsigned short f2bf(float f) {
    __hip_bfloat16 h = __float2bfloat16(f);
    return *reinterpret_cast<unsigned short*>(&h);
}

static __device__ __forceinline__ short8 lds_load8(const unsigned short* p) {
    const short4v a = *(const short4v*)p;
    const short4v b = *(const short4v*)(p + 4);
    short8 r;
    r[0] = a[0]; r[1] = a[1]; r[2] = a[2]; r[3] = a[3];
    r[4] = b[0]; r[5] = b[1]; r[6] = b[2]; r[7] = b[3];
    return r;
}

// ===================== single prep kernel (3 jobs by blockIdx range) ==================
// [0,782):   one pass over s_feats rows -> sfb (bf16) AND rowsum (exact numpy pairwise order)
// [782,814): wbf2 lane-linear B frags: e=(wq*32+s)*64+lane holds 8 bf16 of
//            W''[d=wq*16+(lane&15)][kc=s*32+(lane>>4)*8+j], k=15 zeroed (128 KB)
// 814:       tail: zero sfb row N, rowsum[N]=-1, kpp[k]={-2kx,-2ky,-2kz,|kp|^2}
__global__ void prep_all(const float* __restrict__ sf, const float* __restrict__ w,
                         const float* __restrict__ kpts,
                         unsigned short* __restrict__ sfb, float* __restrict__ rs,
                         unsigned short* __restrict__ wbf2, float4* __restrict__ kpp) {
    const int b = blockIdx.x, t = threadIdx.x;
    if (b < 782) {
        const int tt = b * 256 + t;
        const int row = tt >> 1, p = tt & 1;          // lane p covers cols 4p+8i+0..3
        if (row < NPTS) {
            const float* base = sf + (size_t)row * 64 + p * 4;
            float4 r = *(const float4*)base;          // i = 0
            {
                ushort4 o;
                o.x = f2bf(r.x); o.y = f2bf(r.y); o.z = f2bf(r.z); o.w = f2bf(r.w);
                *(ushort4*)&sfb[(size_t)row * 64 + p * 4] = o;
            }
#pragma unroll
            for (int i = 1; i < 8; i++) {
                const float4 x = *(const float4*)(base + i * 8);
                ushort4 o;
                o.x = f2bf(x.x); o.y = f2bf(x.y); o.z = f2bf(x.z); o.w = f2bf(x.w);
                *(ushort4*)&sfb[(size_t)row * 64 + i * 8 + p * 4] = o;
                r.x += x.x; r.y += x.y; r.z += x.z; r.w += x.w;   // strict per-j fold
            }
            float sp = (r.x + r.y) + (r.z + r.w);
            sp += __shfl_xor(sp, 1);                  // + other half (commutative: exact)
            if (p == 0) rs[row] = sp;
        }
    } else if (b < 814) {
        const int e = (b - 782) * 256 + t;            // 0..8191
        const int lane = e & 63, s = (e >> 6) & 31, wq = e >> 11;
        const int d = wq * 16 + (lane & 15);
        const int lqp = lane >> 4;
        unsigned short o8[8];
#pragma unroll
        for (int j = 0; j < 8; j++) {
            const int kc = s * 32 + lqp * 8 + j;
            const int c = kc >> 4, k = kc & 15;
            o8[j] = (k < KK) ? f2bf(w[k * 4096 + c * 64 + d]) : (unsigned short)0;
        }
#pragma unroll
        for (int j = 0; j < 8; j++) wbf2[(size_t)e * 8 + j] = o8[j];
    } else {
        if (t < 16) *(ushort4*)&sfb[(size_t)NPTS * 64 + t * 4] = make_ushort4(0, 0, 0, 0);
        else if (t == 16) rs[NPTS] = -1.0f;
        else if (t >= 32 && t < 32 + KK) {
            const int k = t - 32;
            const float kx = kpts[k * 3 + 0], ky = kpts[k * 3 + 1], kz = kpts[k * 3 + 2];
            kpp[k] = make_float4(-2.f * kx, -2.f * ky, -2.f * kz, kx * kx + ky * ky + kz * kz);
        }
    }
}

// =======================================================================
// Fused main kernel, TM=16, 512 threads (8 waves). LDS: idx 2048 + stage 36864
// + wtw 33152 + inv 64 = 72128 B -> 2 blocks/CU (16 waves/CU, same cap as TM=8).
// Phase C: all 16 A-rows valid; 8 waves split-K the 4 d-quadrants; 4 KB LDS
// partial reduction reuses the dead stage region. wbf2 L2 traffic halved.
// =======================================================================
__global__ __launch_bounds__(512, 4) void kpconv_fused(
    const float* __restrict__ q_points,
    const float* __restrict__ s_points,
    const unsigned short* __restrict__ sfb,   // (N+1,64) bf16, row N zero
    const int*   __restrict__ nbr,            // (M,32)
    const unsigned short* __restrict__ wbf2,  // lane-linear B frags (128 KB)
    const float4* __restrict__ kpp,           // (15) {-2kx,-2ky,-2kz,|kp|^2}
    const float* __restrict__ rowsum,         // (N+1), entry N = -1
    float* __restrict__ out)                  // (M,64)
{
    const int t    = threadIdx.x;
    const int m0   = blockIdx.x * TM;
    const int lane = t & 63;
    const int wv   = t >> 6;                  // 0..7
    const int l15  = lane & 15;
    const int lq   = lane >> 4;

    __shared__ int idx_lds[TM][32];
    __shared__ __align__(16) unsigned short stage[8][64 * STP];
    __shared__ unsigned short wtw[TM * WTP];
    __shared__ float inv_lds[TM];

    // per-wave idx load (wave-local ordering; no barrier needed)
    const int mw = 2 * wv + (lane >> 5);
    const int h  = lane & 31;
    idx_lds[mw][h] = nbr[(size_t)(m0 + mw) * 32 + h];

    // ---- s_points gather issued FIRST (needed earliest, by the weight compute) ----
    const int idxp = idx_lds[mw][h];
    float px = 1.0e6f, py = 1.0e6f, pz = 1.0e6f;
    if (idxp < NPTS) {
        px = s_points[idxp * 3 + 0];
        py = s_points[idxp * 3 + 1];
        pz = s_points[idxp * 3 + 2];
    }

    // ---- issue BOTH m feature gathers (16 x 8B, rows paired per lane slot) ----
    ushort4 g[2][8];
    const int c4 = l15 * 4;
#pragma unroll
    for (int mi = 0; mi < 2; mi++) {
        const int m = 2 * wv + mi;
#pragma unroll
        for (int g2 = 0; g2 < 4; g2++) {
            const int r0 = g2 * 8 + lq * 2;
            const int2 ip = *(const int2*)&idx_lds[m][r0];
            const int i0 = min(ip.x, NPTS);
            const int i1 = min(ip.y, NPTS);
            g[mi][2 * g2]     = *(const ushort4*)&sfb[(size_t)i0 * 64 + c4];
            g[mi][2 * g2 + 1] = *(const ushort4*)&sfb[(size_t)i1 * 64 + c4];
        }
    }

    // ---- kernel-point weights + counts (covers gather latency) ----
    {
        const float rx = px - q_points[(m0 + mw) * 3 + 0];
        const float ry = py - q_points[(m0 + mw) * 3 + 1];
        const float rz = pz - q_points[(m0 + mw) * 3 + 2];
        const float r2 = rx * rx + ry * ry + rz * rz;
        unsigned short* wrow = &wtw[mw * WTP];
#pragma unroll
        for (int k = 0; k < KK; k++) {
            const float4 kp = kpp[k];                 // wave-uniform -> s_load
            float d2 = kp.w;
            d2 = fmaf(rx, kp.x, d2);
            d2 = fmaf(ry, kp.y, d2);
            d2 = fmaf(rz, kp.z, d2);
            d2 = fmaxf(r2 + d2, 0.0f);                // guard tiny-negative from rounding
            const float wv_ = fmaxf(fmaf(-0.5f, __builtin_amdgcn_sqrtf(d2), 1.0f), 0.0f);
            wrow[k * STP + h] = f2bf(wv_);
        }
        wrow[15 * STP + h] = 0;                       // k-pad row

        const bool ok = rowsum[min(idxp, NPTS)] > 0.0f;  // rowsum[N] = -1
        const unsigned long long bal = __ballot(ok);
        if (h == 0) {
            const int cnt = __popc((unsigned)(bal >> ((lane >> 5) * 32)));
            inv_lds[mw] = 1.0f / (float)(cnt < 1 ? 1 : cnt);
        }
    }

    // ---- wave-private m-loop (no barriers; swizzled stage) ----
    unsigned short* const st = stage[wv];
    const int swzw = (l15 >> 2) << 2;
#pragma unroll
    for (int mi = 0; mi < 2; mi++) {
        const int m = 2 * wv + mi;

        // transpose-write: b32 slot (g2*4+lq)^swz -> <=2-way banks
#pragma unroll
        for (int g2 = 0; g2 < 4; g2++) {
            const int so = ((g2 * 4 + lq) ^ swzw) * 2;
            const ushort4 a = g[mi][2 * g2];
            const ushort4 b = g[mi][2 * g2 + 1];
            *(unsigned*)&st[(c4 + 0) * STP + so] = (unsigned)a.x | ((unsigned)b.x << 16);
            *(unsigned*)&st[(c4 + 1) * STP + so] = (unsigned)a.y | ((unsigned)b.y << 16);
            *(unsigned*)&st[(c4 + 2) * STP + so] = (unsigned)a.z | ((unsigned)b.z << 16);
            *(unsigned*)&st[(c4 + 3) * STP + so] = (unsigned)a.w | ((unsigned)b.w << 16);
        }

        const short8 afrag = lds_load8(&wtw[m * WTP + l15 * STP + lq * 8]);
#pragma unroll
        for (int ct = 0; ct < 4; ct++) {
            const short8 bfrag = lds_load8(&st[(ct * 16 + l15) * STP + ((lq ^ ct) * 8)]);
            floatx4 d = {0.f, 0.f, 0.f, 0.f};
            d = __builtin_amdgcn_mfma_f32_16x16x32_bf16(afrag, bfrag, d, 0, 0, 0);
            ushort4 pk;                               // raw weighted (1/cnt applied in epilogue)
            pk.x = f2bf(d[0]); pk.y = f2bf(d[1]); pk.z = f2bf(d[2]); pk.w = f2bf(d[3]);
            *(ushort4*)&wtw[m * WTP + (ct * 16 + l15) * 16 + lq * 4] = pk;
        }
    }
    __syncthreads();   // barrier 1: all 16 weighted rows + inv visible

    // ---- Phase C: out[m][d] = inv[m] * sum_kc weighted[m][kc] * W''[kc][d] ----
    // 8 waves: q = d-quadrant, kh = K-half. All 16 D-rows valid (no junk rows).
    {
        const int q  = wv & 3;
        const int kh = wv >> 2;
        floatx4 acc = {0.f, 0.f, 0.f, 0.f};
        const unsigned short* ap = &wtw[l15 * WTP + kh * 512 + lq * 8];
        const unsigned short* bp = wbf2 + ((size_t)((q * 32 + kh * 16) * 64) + lane) * 8;
#pragma unroll 8
        for (int s = 0; s < 16; s++) {
            const short8 a = lds_load8(ap + s * 32);
            const short8 b = *(const short8*)(bp + s * 512);   // coalesced 1 KB/wave, L2-hot
            acc = __builtin_amdgcn_mfma_f32_16x16x32_bf16(a, b, acc, 0, 0, 0);
        }

        // split-K reduction through the dead stage region (4 KB: [q][l15][m] f32)
        float* const scratch = (float*)&stage[0][0];
        if (kh == 1) {
            *(floatx4*)&scratch[q * 256 + l15 * 16 + lq * 4] = acc;   // b128, uniform banks
        }
        __syncthreads();   // barrier 2: partials visible
        if (kh == 0) {
            const floatx4 p = *(const floatx4*)&scratch[q * 256 + l15 * 16 + lq * 4];
            const int d = q * 16 + l15;
#pragma unroll
            for (int r = 0; r < 4; r++) {
                const int m = lq * 4 + r;
                out[(size_t)(m0 + m) * 64 + d] = (acc[r] + p[r]) * inv_lds[m];
            }
        }
    }
}

extern "C" void kernel_launch(void* const* d_in, const int* in_sizes, int n_in,
                              void* d_out, int out_size, void* d_ws, size_t ws_size,
                              hipStream_t stream) {
    const float* q_points = (const float*)d_in[0];
    const float* s_points = (const float*)d_in[1];
    const float* s_feats  = (const float*)d_in[2];
    const int*   nbr      = (const int*)d_in[3];
    const float* weights  = (const float*)d_in[4];
    const float* kpts     = (const float*)d_in[5];
    float* out = (float*)d_out;

    char* ws = (char*)d_ws;
    unsigned short* wbf2 = (unsigned short*)ws;              // [0, 131072)
    float* rowsum = (float*)(ws + 131072);                   // (N+1) floats
    float4* kpp = (float4*)(ws + 531600);                    // 240 B, 16B-aligned
    unsigned short* sfb = (unsigned short*)(ws + 532480);    // (N+1)*64 bf16 = 12.8 MB

    prep_all<<<815, 256, 0, stream>>>(s_feats, weights, kpts, sfb, rowsum, wbf2, kpp);
    kpconv_fused<<<MPTS / TM, 512, 0, stream>>>(q_points, s_points, sfb, nbr,
                                                wbf2, kpp, rowsum, out);
}